// Round 21
// baseline (68.975 us; speedup 1.0000x reference)
//
#include <hip/hip_runtime.h>

#define BS 4096
#define LL 512
#define NB 16                 // batches per block = MFMA columns
#define NCH 32                // chunks of 16 steps
#define CS 16                 // steps per chunk
#define QR 128                // staged rows per quarter-slot
#define SCWD 131              // dwords per staged t-row (128 data + 3 pad, odd stride)
#define START_TAG 1
#define END_TAG 2
#define BIASF 4.5f            // per-applied-step 2^-BIASF (restored exactly in log2)
#define L2E 1.44269504f
#define LN2 0.69314718055994531f

typedef float f32x4 __attribute__((ext_vector_type(4)));
typedef short s16x4 __attribute__((ext_vector_type(4)));
union BF4 { unsigned u[2]; s16x4 s; };

__device__ __forceinline__ unsigned cvt_pk_bf16(float lo, float hi) {
    unsigned r;
    asm("v_cvt_pk_bf16_f32 %0, %1, %2" : "=v"(r) : "v"(lo), "v"(hi));
    return r;
}
__device__ __forceinline__ float blo(unsigned u) { return __uint_as_float(u << 16); }
__device__ __forceinline__ float bhi(unsigned u) { return __uint_as_float(u & 0xFFFF0000u); }

#define CSTEP(SV, P01, P23) { \
        const float f0 = blo((SV).x), f1 = bhi((SV).x); \
        const float f2 = blo((SV).y), f3 = bhi((SV).y); \
        BF4 Bf; Bf.u[0] = P01; Bf.u[1] = P23; \
        f32x4 z = {0.f, 0.f, 0.f, 0.f}; \
        f32x4 d = __builtin_amdgcn_mfma_f32_16x16x16bf16_1k(Af.s, Bf.s, z, 0, 0, 0); \
        P01 = cvt_pk_bf16(d[0] * f0, d[1] * f1); \
        P23 = cvt_pk_bf16(d[2] * f2, d[3] * f3); }

#define CSTEPM(SV, MB, S, P01, P23) { \
        const float f0 = blo((SV).x), f1 = bhi((SV).x); \
        const float f2 = blo((SV).y), f3 = bhi((SV).y); \
        BF4 Bf; Bf.u[0] = P01; Bf.u[1] = P23; \
        f32x4 z = {0.f, 0.f, 0.f, 0.f}; \
        f32x4 d = __builtin_amdgcn_mfma_f32_16x16x16bf16_1k(Af.s, Bf.s, z, 0, 0, 0); \
        const unsigned n01 = cvt_pk_bf16(d[0] * f0, d[1] * f1); \
        const unsigned n23 = cvt_pk_bf16(d[2] * f2, d[3] * f3); \
        const bool up = (((MB) >> (S)) & 1u) != 0u; \
        P01 = up ? n01 : P01; \
        P23 = up ? n23 : P23; }

#define RENORM(P01, P23, E2F) { \
        const float v0 = blo(P01), v1 = bhi(P01), v2 = blo(P23), v3 = bhi(P23); \
        float mm = fmaxf(fmaxf(v0, v1), fmaxf(v2, v3)); \
        mm = fmaxf(mm, __shfl_xor(mm, 16)); \
        mm = fmaxf(mm, __shfl_xor(mm, 32)); \
        if (mm > 0.f) { \
            const int ex = (int)((__float_as_uint(mm) >> 23) & 0xFFu) - 127; \
            const float sre = __uint_as_float((unsigned)(127 - ex) << 23); \
            E2F += (float)ex; \
            P01 = cvt_pk_bf16(v0 * sre, v1 * sre); \
            P23 = cvt_pk_bf16(v2 * sre, v3 * sre); } }

// run one 16-step chunk chain (r17-validated math; 1-ahead rolling prefetch)
#define CHAIN16(BASE, MBC, P01, P23, E2F) { \
        uint2 sv = *(const uint2*)(sSC + (BASE)); \
        if (__all((MBC) == 0xFFFFu)) { \
            _Pragma("unroll") \
            for (int s = 0; s < 16; ++s) { \
                const uint2 nx = (s < 15) ? *(const uint2*)(sSC + (BASE) + (s + 1) * SCWD) : sv; \
                CSTEP(sv, P01, P23) \
                sv = nx; \
            } \
        } else { \
            _Pragma("unroll") \
            for (int s = 0; s < 16; ++s) { \
                const uint2 nx = (s < 15) ? *(const uint2*)(sSC + (BASE) + (s + 1) * SCWD) : sv; \
                CSTEPM(sv, MBC, s, P01, P23) \
                sv = nx; \
            } \
        } \
        RENORM(P01, P23, E2F) }

#define STAGE_ONE(SLOT, QID, V) { \
        const int bl_ = (QID) >> 9; \
        const int trow_ = ((QID) >> 2) & 127; \
        const int c4_ = (QID) & 3; \
        const float e0 = exp2f(fmaf((V).x, L2E, -BIASF)); \
        const float e1 = exp2f(fmaf((V).y, L2E, -BIASF)); \
        const float e2 = exp2f(fmaf((V).z, L2E, -BIASF)); \
        const float e3 = exp2f(fmaf((V).w, L2E, -BIASF)); \
        uint2 w_; w_.x = cvt_pk_bf16(e0, e1); w_.y = cvt_pk_bf16(e2, e3); \
        *(uint2*)(sSC + (SLOT) * (QR * SCWD) + trow_ * SCWD + bl_ * 8 + 2 * c4_) = w_; }

// Role-split pipelined CRF: block = 16 batches, 16 waves.
// Waves 0-7 CHAIN (wave w -> chunk 8Q+w, pass1 then pass2, r17 math verbatim);
// waves 8-15 STAGE quarter Q+1 into the other slot during both phases.
// Score reads raw em after the loop (L2/L3-hot). Telescoped rank-1 combine.
__global__ __launch_bounds__(1024) void crf_ov(
    const float* __restrict__ em, const int* __restrict__ tg,
    const float* __restrict__ mk, const float* __restrict__ tr,
    float* __restrict__ out)
{
    __shared__ unsigned sSC[2 * QR * SCWD];        // 134144 B staged bf16 scales
    __shared__ unsigned sYr[16 * NB * 8];          // 8 KB y-vector ring (c & 15)
    __shared__ float sEnd[NB][16];                 // chunk-31 end vectors
    __shared__ float sYs[NCH][NB], sRs[NCH][NB], sF[NCH][NB], sG[NCH][NB];
    __shared__ unsigned short sMB[NCH][NB];        // per-(chunk,batch) mask bits
    __shared__ float sTR[256];
    __shared__ float sSc[NB], sRes[NB];

    const int tid = threadIdx.x;
    const int wv = tid >> 6, lane = tid & 63;
    const int j = lane & 15, q = lane >> 4;
    const long gb0 = (long)blockIdx.x * NB;

    if (tid < 64) *(f32x4*)(sTR + tid * 4) = *(const f32x4*)(tr + tid * 4);

    int is64 = 1;
    {
        const unsigned long long* t64 = (const unsigned long long*)tg;
#pragma unroll
        for (int i = 0; i < 16; ++i) is64 &= (t64[i] < 16ull) ? 1 : 0;
    }
    const int esz = is64 ? 2 : 1;

    // mask bitmask: wave wv = batch wv (r17 verbatim)
    {
        const float* mp = mk + (gb0 + wv) * (long)LL;
#pragma unroll
        for (int k = 0; k < 8; ++k) {
            const unsigned long long bal = __ballot(mp[k * 64 + lane] > 0.f);
            if (lane == 0) {
                sMB[4 * k + 0][wv] = (unsigned short)(bal);
                sMB[4 * k + 1][wv] = (unsigned short)(bal >> 16);
                sMB[4 * k + 2][wv] = (unsigned short)(bal >> 32);
                sMB[4 * k + 3][wv] = (unsigned short)(bal >> 48);
            }
        }
    }
    __syncthreads();

    // static A = E^T (validated): lane (j,q) holds A[j][4q+i] = exp(tr[4q+i][j])
    BF4 Af;
    {
        float Ef[4];
#pragma unroll
        for (int i = 0; i < 4; ++i)
            Ef[i] = exp2f(sTR[(q * 4 + i) * 16 + j] * L2E);   // exp(-1000) -> 0
        Af.u[0] = cvt_pk_bf16(Ef[0], Ef[1]);
        Af.u[1] = cvt_pk_bf16(Ef[2], Ef[3]);
    }
    const int jqoff = j * 8 + 2 * q;

    // ---- prologue: all 16 waves stage quarter 0 -> slot 0 ----
    {
        f32x4 vv[8];
#pragma unroll
        for (int it = 0; it < 8; ++it) {
            const int qid = tid + it * 1024;
            const int bl = qid >> 9, trow = (qid >> 2) & 127, c4 = qid & 3;
            vv[it] = *(const f32x4*)(em + ((gb0 + bl) * (long)LL + trow) * 16 + 4 * c4);
        }
#pragma unroll
        for (int it = 0; it < 8; ++it) STAGE_ONE(0, tid + it * 1024, vv[it])
    }
    __syncthreads();

    // ---- main pipeline: 4 quarters ----
    for (int Q = 0; Q < 4; ++Q) {
        const int slot = Q & 1;
        const bool chainw = (wv < 8);              // wave-uniform role
        const int c = 8 * Q + (wv & 7);            // chunk id (chain waves)
        const unsigned mbc = (unsigned)sMB[c][j];
        const int base = slot * (QR * SCWD) + ((wv & 7) * CS) * SCWD + jqoff;
        const int sid = ((wv & 7) << 6) + lane;    // stage-wave work index

        // phase A: pass1 (chains) || stage first half of quarter Q+1
        if (chainw) {
            unsigned p01 = 0x3F803F80u, p23 = 0x3F803F80u;
            float e2f = 0.f;
            CHAIN16(base, mbc, p01, p23, e2f)
            uint2 y; y.x = p01; y.y = p23;
            *(uint2*)(sYr + ((c & 15) * NB + j) * 8 + 2 * q) = y;
            float sa = blo(p01) + bhi(p01) + blo(p23) + bhi(p23);
            sa += __shfl_xor(sa, 16);
            sa += __shfl_xor(sa, 32);
            if (lane < 16) {
                sYs[c][j] = sa;
                sF[c][j] = e2f + BIASF * (float)__popc(mbc);
            }
            if (c == NCH - 1) {
                sEnd[j][4 * q + 0] = blo(p01);
                sEnd[j][4 * q + 1] = bhi(p01);
                sEnd[j][4 * q + 2] = blo(p23);
                sEnd[j][4 * q + 3] = bhi(p23);
            }
        } else if (Q < 3) {
            f32x4 vv[8];
#pragma unroll
            for (int it = 0; it < 8; ++it) {
                const int qid = sid + it * 512;            // [0, 4096)
                const int bl = qid >> 9, trow = (qid >> 2) & 127, c4 = qid & 3;
                vv[it] = *(const f32x4*)(em + ((gb0 + bl) * (long)LL + (Q + 1) * QR + trow) * 16 + 4 * c4);
            }
#pragma unroll
            for (int it = 0; it < 8; ++it) STAGE_ONE(slot ^ 1, sid + it * 512, vv[it])
        }
        __syncthreads();

        // phase B: pass2 (chains, from y_{c-1}) || stage second half of Q+1
        if (chainw) {
            if (c > 0) {                                   // wave-uniform
                const uint2 y = *(const uint2*)(sYr + (((c - 1) & 15) * NB + j) * 8 + 2 * q);
                unsigned r01 = y.x, r23 = y.y;
                float g2f = 0.f;
                CHAIN16(base, mbc, r01, r23, g2f)
                float sb = blo(r01) + bhi(r01) + blo(r23) + bhi(r23);
                sb += __shfl_xor(sb, 16);
                sb += __shfl_xor(sb, 32);
                if (lane < 16) {
                    sRs[c][j] = sb;
                    sG[c][j] = g2f + BIASF * (float)__popc(mbc);
                }
            }
        } else if (Q < 3) {
            f32x4 vv[8];
#pragma unroll
            for (int it = 0; it < 8; ++it) {
                const int qid = sid + (8 + it) * 512;      // [4096, 8192)
                const int bl = qid >> 9, trow = (qid >> 2) & 127, c4 = qid & 3;
                vv[it] = *(const f32x4*)(em + ((gb0 + bl) * (long)LL + (Q + 1) * QR + trow) * 16 + 4 * c4);
            }
#pragma unroll
            for (int it = 0; it < 8; ++it) STAGE_ONE(slot ^ 1, sid + (8 + it) * 512, vv[it])
        }
        __syncthreads();
    }

    // ---- score: wave wv = batch wv, raw em (exact fp32; r20-validated) ----
    float scoreAcc = 0.f;
    {
        const long bb = (gb0 + wv) * (long)LL;
#pragma unroll
        for (int k2 = 0; k2 < 8; ++k2) {
            const int t = k2 * 64 + lane;
            const int tcur = tg[(bb + t) * esz];
            const long pidx = (bb + (t == 0 ? 1 : t) - 1) * esz;
            const int tpv = (t == 0) ? START_TAG : (int)tg[pidx];
            const float mbit = (float)((sMB[t >> 4][wv] >> (t & 15)) & 1);
            const float scm = (t == 0) ? 1.f : mbit;
            scoreAcc = fmaf(em[(bb + t) * 16 + tcur] + sTR[tpv * 16 + tcur], scm, scoreAcc);
        }
#pragma unroll
        for (int o = 1; o <= 32; o <<= 1) scoreAcc += __shfl_xor(scoreAcc, o);
        if (lane == 0) sSc[wv] = scoreAcc;
    }
    __syncthreads();

    // ---- combine (r17-validated telescope): 256 threads = 16 b x 16 rows ----
    if (tid < 256) {
        const int b = tid >> 4, row = tid & 15;
        float x = sEnd[b][row] * exp2f(sTR[row * 16 + END_TAG] * L2E);
#pragma unroll
        for (int o = 1; o <= 8; o <<= 1) x += __shfl_xor(x, o, 16);
        if (row == 0) {
            float l2 = log2f(fmaxf(x, 1e-37f)) + sF[NCH - 1][b];
#pragma unroll
            for (int c2 = 1; c2 < NCH; ++c2)
                l2 += log2f(fmaxf(sRs[c2][b], 1e-37f))
                    - log2f(fmaxf(sYs[c2][b], 1e-37f))
                    + sG[c2][b] + sF[c2 - 1][b] - sF[c2][b];
            int cnt = 0;
#pragma unroll
            for (int c2 = 0; c2 < NCH; ++c2) cnt += __popc((unsigned)sMB[c2][b]);
            const int li = (cnt > 0) ? (cnt - 1) : 0;
            const int lt = tg[((gb0 + b) * (long)LL + li) * esz];
            sRes[b] = LN2 * l2 - (sSc[b] + sTR[lt * 16 + END_TAG]);
        }
    }
    __syncthreads();
    if (tid == 0) {
        float s = 0.f;
#pragma unroll
        for (int i = 0; i < NB; ++i) s += sRes[i];
        atomicAdd(out, s);
    }
}

extern "C" void kernel_launch(void* const* d_in, const int* in_sizes, int n_in,
                              void* d_out, int out_size, void* d_ws, size_t ws_size,
                              hipStream_t stream) {
    const float* em = (const float*)d_in[0];
    const int*   tg = (const int*)d_in[1];
    const float* mk = (const float*)d_in[2];
    const float* tr = (const float*)d_in[3];
    float* out = (float*)d_out;

    hipMemsetAsync(out, 0, sizeof(float), stream);
    crf_ov<<<BS / NB, 1024, 0, stream>>>(em, tg, mk, tr, out);
}

// Round 22
// 53.607 us; speedup vs baseline: 1.2867x; 1.2867x over previous
//
#include <hip/hip_runtime.h>

#define BS 4096
#define LL 512
#define NB 16                 // batches per block = MFMA columns
#define NCH 32                // chunks of 16 steps
#define RSD 66                // dwords per staged t-row (64 data + 2 pad; 2-way banks)
#define START_TAG 1
#define END_TAG 2
#define BIASF 4.5f            // per-applied-step 2^-BIASF (restored exactly in log2)
#define L2E 1.44269504f
#define LN2 0.69314718055994531f

typedef float f32x4 __attribute__((ext_vector_type(4)));
typedef short s16x4 __attribute__((ext_vector_type(4)));
union BF4 { unsigned u[2]; s16x4 s; };

__device__ __forceinline__ unsigned cvt_pk_bf16(float lo, float hi) {
    unsigned r;
    asm("v_cvt_pk_bf16_f32 %0, %1, %2" : "=v"(r) : "v"(lo), "v"(hi));
    return r;
}
__device__ __forceinline__ unsigned pkrtz(float lo, float hi) {
    unsigned r;
    asm("v_cvt_pkrtz_f16_f32 %0, %1, %2" : "=v"(r) : "v"(lo), "v"(hi));
    return r;
}
__device__ __forceinline__ float cf16(unsigned bits) {
    float f;
    asm("v_cvt_f32_f16 %0, %1" : "=v"(f) : "v"(bits));
    return f;
}
__device__ __forceinline__ float blo(unsigned u) { return __uint_as_float(u << 16); }
__device__ __forceinline__ float bhi(unsigned u) { return __uint_as_float(u & 0xFFFF0000u); }

// fp8(e5m2)-scale chain step: decode 4 scales from one b32, MFMA, repack bf16
#define CSTEP8(S8, P01, P23) { \
        const float f0 = cf16(((S8) & 0xFFu) << 8); \
        const float f1 = cf16((S8) & 0xFF00u); \
        const float f2 = cf16(((S8) >> 8) & 0xFF00u); \
        const float f3 = cf16(((S8) >> 16) & 0xFF00u); \
        BF4 Bf; Bf.u[0] = P01; Bf.u[1] = P23; \
        f32x4 z = {0.f, 0.f, 0.f, 0.f}; \
        f32x4 d = __builtin_amdgcn_mfma_f32_16x16x16bf16_1k(Af.s, Bf.s, z, 0, 0, 0); \
        P01 = cvt_pk_bf16(d[0] * f0, d[1] * f1); \
        P23 = cvt_pk_bf16(d[2] * f2, d[3] * f3); }

#define CSTEP8M(S8, MB, S, P01, P23) { \
        const float f0 = cf16(((S8) & 0xFFu) << 8); \
        const float f1 = cf16((S8) & 0xFF00u); \
        const float f2 = cf16(((S8) >> 8) & 0xFF00u); \
        const float f3 = cf16(((S8) >> 16) & 0xFF00u); \
        BF4 Bf; Bf.u[0] = P01; Bf.u[1] = P23; \
        f32x4 z = {0.f, 0.f, 0.f, 0.f}; \
        f32x4 d = __builtin_amdgcn_mfma_f32_16x16x16bf16_1k(Af.s, Bf.s, z, 0, 0, 0); \
        const unsigned n01 = cvt_pk_bf16(d[0] * f0, d[1] * f1); \
        const unsigned n23 = cvt_pk_bf16(d[2] * f2, d[3] * f3); \
        const bool up = (((MB) >> (S)) & 1u) != 0u; \
        P01 = up ? n01 : P01; \
        P23 = up ? n23 : P23; }

#define RENORM(P01, P23, E2F) { \
        const float v0 = blo(P01), v1 = bhi(P01), v2 = blo(P23), v3 = bhi(P23); \
        float mm = fmaxf(fmaxf(v0, v1), fmaxf(v2, v3)); \
        mm = fmaxf(mm, __shfl_xor(mm, 16)); \
        mm = fmaxf(mm, __shfl_xor(mm, 32)); \
        if (mm > 0.f) { \
            const int ex = (int)((__float_as_uint(mm) >> 23) & 0xFFu) - 127; \
            const float sre = __uint_as_float((unsigned)(127 - ex) << 23); \
            E2F += (float)ex; \
            P01 = cvt_pk_bf16(v0 * sre, v1 * sre); \
            P23 = cvt_pk_bf16(v2 * sre, v3 * sre); } }

// one 16-step chunk chain from fp8 LDS scales (1-ahead rolling prefetch)
#define CHAIN16F8(BASE, MBC, P01, P23, E2F) { \
        unsigned sv = sSCu[(BASE)]; \
        if (__all((MBC) == 0xFFFFu)) { \
            _Pragma("unroll") \
            for (int s = 0; s < 16; ++s) { \
                const unsigned nx = (s < 15) ? sSCu[(BASE) + (s + 1) * RSD] : sv; \
                CSTEP8(sv, P01, P23) \
                sv = nx; \
            } \
        } else { \
            _Pragma("unroll") \
            for (int s = 0; s < 16; ++s) { \
                const unsigned nx = (s < 15) ? sSCu[(BASE) + (s + 1) * RSD] : sv; \
                CSTEP8M(sv, MBC, s, P01, P23) \
                sv = nx; \
            } \
        } \
        RENORM(P01, P23, E2F) }

// Single-stage CRF: block = 16 batches, 16 waves, 5 barrier phases.
// Stage ALL 512 steps of exp-scales as fp8 e5m2 -> LDS (132 KB); pass1: wave w
// chains chunks {w, w+16} from ones; pass2: same chunks from y_{c-1}; score
// from staged scales; r17-validated telescoped rank-1 combine.
__global__ __launch_bounds__(1024) void crf_f8(
    const float* __restrict__ em, const int* __restrict__ tg,
    const float* __restrict__ mk, const float* __restrict__ tr,
    float* __restrict__ out)
{
    __shared__ unsigned sSCu[LL * RSD];            // 135168 B fp8 scales
    __shared__ unsigned sYp[NCH * NB * 8];         // 16 KB packed bf16 y-vectors
    __shared__ float sYs[NCH][NB], sRs[NCH][NB], sF[NCH][NB], sG[NCH][NB];
    __shared__ unsigned short sMB[NCH][NB];        // per-(chunk,batch) mask bits
    __shared__ float sTR[256];
    __shared__ float sSc[NB], sRes[NB];

    const int tid = threadIdx.x;
    const int wv = tid >> 6, lane = tid & 63;
    const int j = lane & 15, q = lane >> 4;
    const long gb0 = (long)blockIdx.x * NB;

    if (tid < 64) *(f32x4*)(sTR + tid * 4) = *(const f32x4*)(tr + tid * 4);

    int is64 = 1;
    {
        const unsigned long long* t64 = (const unsigned long long*)tg;
#pragma unroll
        for (int i = 0; i < 16; ++i) is64 &= (t64[i] < 16ull) ? 1 : 0;
    }
    const int esz = is64 ? 2 : 1;

    // mask bitmask: wave wv = batch wv (r17 verbatim)
    {
        const float* mp = mk + (gb0 + wv) * (long)LL;
#pragma unroll
        for (int k = 0; k < 8; ++k) {
            const unsigned long long bal = __ballot(mp[k * 64 + lane] > 0.f);
            if (lane == 0) {
                sMB[4 * k + 0][wv] = (unsigned short)(bal);
                sMB[4 * k + 1][wv] = (unsigned short)(bal >> 16);
                sMB[4 * k + 2][wv] = (unsigned short)(bal >> 32);
                sMB[4 * k + 3][wv] = (unsigned short)(bal >> 48);
            }
        }
    }
    __syncthreads();

    // static A = E^T (validated): lane (j,q) holds A[j][4q+i] = exp(tr[4q+i][j])
    BF4 Af;
    {
        float Ef[4];
#pragma unroll
        for (int i = 0; i < 4; ++i)
            Ef[i] = exp2f(sTR[(q * 4 + i) * 16 + j] * L2E);   // exp(-1000) -> 0
        Af.u[0] = cvt_pk_bf16(Ef[0], Ef[1]);
        Af.u[1] = cvt_pk_bf16(Ef[2], Ef[3]);
    }

    // ---- stage ALL 512 steps: coalesced em -> exp2 -> fp8 e5m2 -> LDS ----
#pragma unroll 4
    for (int it = 0; it < 32; ++it) {
        const int qid = tid + it * 1024;           // [b:4][t:9][q:2]
        const int bl = qid >> 11, trow = (qid >> 2) & 511, c4 = qid & 3;
        const f32x4 v = *(const f32x4*)(em + ((gb0 + bl) * (long)LL + trow) * 16 + 4 * c4);
        const float e0 = exp2f(fmaf(v.x, L2E, -BIASF));
        const float e1 = exp2f(fmaf(v.y, L2E, -BIASF));
        const float e2 = exp2f(fmaf(v.z, L2E, -BIASF));
        const float e3 = exp2f(fmaf(v.w, L2E, -BIASF));
        const unsigned t0 = pkrtz(e0, e1) + 0x00800080u;   // round bit7 half-up
        const unsigned t1 = pkrtz(e2, e3) + 0x00800080u;
        const unsigned b = ((t0 >> 8) & 0xFFu) | (((t0 >> 24) & 0xFFu) << 8)
                         | (((t1 >> 8) & 0xFFu) << 16) | ((t1 >> 24) << 24);
        sSCu[trow * RSD + bl * 4 + c4] = b;
    }
    __syncthreads();

    // ---- pass1: wave wv chains chunks {wv, wv+16} from ones ----
#pragma unroll
    for (int half = 0; half < 2; ++half) {
        const int c = wv + half * 16;
        const unsigned mbc = (unsigned)sMB[c][j];
        const int base = (c * 16) * RSD + j * 4 + q;
        unsigned p01 = 0x3F803F80u, p23 = 0x3F803F80u;
        float e2f = 0.f;
        CHAIN16F8(base, mbc, p01, p23, e2f)
        uint2 y; y.x = p01; y.y = p23;
        *(uint2*)(sYp + (c * 16 + j) * 8 + 2 * q) = y;
        float sa = blo(p01) + bhi(p01) + blo(p23) + bhi(p23);
        sa += __shfl_xor(sa, 16);
        sa += __shfl_xor(sa, 32);
        if (lane < 16) {
            sYs[c][j] = sa;
            sF[c][j] = e2f + BIASF * (float)__popc(mbc);
        }
    }
    __syncthreads();

    // ---- pass2: same chunks from y_{c-1}; score fused into this phase ----
#pragma unroll
    for (int half = 0; half < 2; ++half) {
        const int c = wv + half * 16;
        if (c > 0) {                               // wave-uniform
            const unsigned mbc = (unsigned)sMB[c][j];
            const int base = (c * 16) * RSD + j * 4 + q;
            const uint2 y = *(const uint2*)(sYp + ((c - 1) * 16 + j) * 8 + 2 * q);
            unsigned r01 = y.x, r23 = y.y;
            float g2f = 0.f;
            CHAIN16F8(base, mbc, r01, r23, g2f)
            float sb = blo(r01) + bhi(r01) + blo(r23) + bhi(r23);
            sb += __shfl_xor(sb, 16);
            sb += __shfl_xor(sb, 32);
            if (lane < 16) {
                sRs[c][j] = sb;
                sG[c][j] = g2f + BIASF * (float)__popc(mbc);
            }
        }
    }
    // score: wave wv = batch wv, em reconstructed from fp8 scales
    float scoreAcc = 0.f;
    {
        const long bb = (gb0 + wv) * (long)LL;
        const unsigned char* sc8 = (const unsigned char*)sSCu;
#pragma unroll
        for (int k = 0; k < 8; ++k) {
            const int t = k * 64 + lane;
            const int tcur = tg[(bb + t) * esz];
            const long pidx = (bb + (t == 0 ? 1 : t) - 1) * esz;   // in-bounds
            const int tpv = (t == 0) ? START_TAG : (int)tg[pidx];
            const float mbit = (float)((sMB[t >> 4][wv] >> (t & 15)) & 1);
            const float scm = (t == 0) ? 1.f : mbit;
            const float sc = cf16(((unsigned)sc8[t * (RSD * 4) + wv * 16 + tcur]) << 8);
            const float emr = (log2f(fmaxf(sc, 1e-30f)) + BIASF) * LN2;
            scoreAcc = fmaf(emr + sTR[tpv * 16 + tcur], scm, scoreAcc);
        }
#pragma unroll
        for (int o = 1; o <= 32; o <<= 1) scoreAcc += __shfl_xor(scoreAcc, o);
        if (lane == 0) sSc[wv] = scoreAcc;
    }
    __syncthreads();

    // ---- combine (r17-validated telescope): 256 threads = 16 b x 16 rows ----
    if (tid < 256) {
        const int b = tid >> 4, row = tid & 15;
        const unsigned short* yp16 = (const unsigned short*)sYp;
        float x = __uint_as_float(((unsigned)yp16[((NCH - 1) * 16 + b) * 16 + row]) << 16)
                * exp2f(sTR[row * 16 + END_TAG] * L2E);
#pragma unroll
        for (int o = 1; o <= 8; o <<= 1) x += __shfl_xor(x, o, 16);
        if (row == 0) {
            float l2 = log2f(fmaxf(x, 1e-37f)) + sF[NCH - 1][b];
#pragma unroll
            for (int c2 = 1; c2 < NCH; ++c2)
                l2 += log2f(fmaxf(sRs[c2][b], 1e-37f))
                    - log2f(fmaxf(sYs[c2][b], 1e-37f))
                    + sG[c2][b] + sF[c2 - 1][b] - sF[c2][b];
            int cnt = 0;
#pragma unroll
            for (int c2 = 0; c2 < NCH; ++c2) cnt += __popc((unsigned)sMB[c2][b]);
            const int li = (cnt > 0) ? (cnt - 1) : 0;
            const int lt = tg[((gb0 + b) * (long)LL + li) * esz];
            sRes[b] = LN2 * l2 - (sSc[b] + sTR[lt * 16 + END_TAG]);
        }
    }
    __syncthreads();
    if (tid == 0) {
        float s = 0.f;
#pragma unroll
        for (int i = 0; i < NB; ++i) s += sRes[i];
        atomicAdd(out, s);
    }
}

extern "C" void kernel_launch(void* const* d_in, const int* in_sizes, int n_in,
                              void* d_out, int out_size, void* d_ws, size_t ws_size,
                              hipStream_t stream) {
    const float* em = (const float*)d_in[0];
    const int*   tg = (const int*)d_in[1];
    const float* mk = (const float*)d_in[2];
    const float* tr = (const float*)d_in[3];
    float* out = (float*)d_out;

    hipMemsetAsync(out, 0, sizeof(float), stream);
    crf_f8<<<BS / NB, 1024, 0, stream>>>(em, tg, mk, tr, out);
}